// Round 4
// baseline (241.396 us; speedup 1.0000x reference)
//
#include <hip/hip_runtime.h>
#include <math.h>

#define NFEAT 512
#define NHID  128
#define NCLASS 16
#define SCAN_BS 512

typedef __attribute__((ext_vector_type(8))) short short8;
typedef __attribute__((ext_vector_type(4))) float f32x4;

static __device__ __forceinline__ ushort f2b(float f) {
    union { float f; uint u; } v; v.f = f;
    uint r = v.u + 0x7FFFu + ((v.u >> 16) & 1u);   // round-to-nearest-even
    return (ushort)(r >> 16);
}
static __device__ __forceinline__ float b2f(uint bits) {
    union { uint u; float f; } v; v.u = bits << 16; return v.f;
}

// ---------------- CSR build ----------------

__global__ void k_init_deg(int* __restrict__ deg, int n) {
    int i = blockIdx.x * blockDim.x + threadIdx.x;
    if (i < n) deg[i] = 1;  // self-loop
}

__global__ void k_count(const int* __restrict__ dst, int e, int* __restrict__ deg) {
    int i = blockIdx.x * blockDim.x + threadIdx.x;
    if (i < e) atomicAdd(&deg[dst[i]], 1);
}

__global__ void k_dinv(const int* __restrict__ deg, float* __restrict__ dinv,
                       int* __restrict__ cursor, int n) {
    int i = blockIdx.x * blockDim.x + threadIdx.x;
    if (i < n) {
        dinv[i] = rsqrtf((float)deg[i]);
        cursor[i] = 0;
    }
}

__global__ void k_scan1(const int* __restrict__ deg, int* __restrict__ offs,
                        int* __restrict__ bsum, int n) {
    __shared__ int s[SCAN_BS];
    int t = threadIdx.x;
    int i = blockIdx.x * SCAN_BS + t;
    int v = (i < n) ? deg[i] : 0;
    s[t] = v;
    for (int off = 1; off < SCAN_BS; off <<= 1) {
        __syncthreads();
        int x = (t >= off) ? s[t - off] : 0;
        __syncthreads();
        s[t] += x;
    }
    __syncthreads();
    if (i < n) offs[i] = s[t] - v;
    if (t == SCAN_BS - 1) bsum[blockIdx.x] = s[t];
}

__global__ void k_scan2(int* __restrict__ bsum, int* __restrict__ offs, int nb, int n) {
    if (threadIdx.x == 0 && blockIdx.x == 0) {
        int run = 0;
        for (int b = 0; b < nb; b++) { int x = bsum[b]; bsum[b] = run; run += x; }
        offs[n] = run;
    }
}

__global__ void k_scan3(int* __restrict__ offs, const int* __restrict__ bsum, int n) {
    int i = blockIdx.x * SCAN_BS + threadIdx.x;
    if (i < n) offs[i] += bsum[blockIdx.x];
}

__global__ void k_fill_edges(const int* __restrict__ src, const int* __restrict__ dst, int e,
                             const int* __restrict__ offs, int* __restrict__ cursor,
                             int* __restrict__ col) {
    int i = blockIdx.x * blockDim.x + threadIdx.x;
    if (i < e) {
        int d = dst[i];
        int p = atomicAdd(&cursor[d], 1);
        col[offs[d] + p] = src[i];
    }
}

__global__ void k_fill_self(const int* __restrict__ offs, int* __restrict__ cursor,
                            int* __restrict__ col, int n) {
    int i = blockIdx.x * blockDim.x + threadIdx.x;
    if (i < n) {
        int p = atomicAdd(&cursor[i], 1);
        col[offs[i] + p] = i;
    }
}

// ---------------- weight transpose+cast: W[K][128] f32 -> WT[128][K] bf16 ----------------

__global__ void k_tcast(const float* __restrict__ W, ushort* __restrict__ WT, int K) {
    int idx = blockIdx.x * 256 + threadIdx.x;
    if (idx < K * 128) {
        int k = idx >> 7, c = idx & 127;
        WT[(size_t)c * K + k] = f2b(W[idx]);
    }
}

// ---------------- bf16 MFMA GEMM: H[M,128] = (A[M,K] @ W[K,128]) * rowscale[row] ----

template<int A_F32>
__global__ __launch_bounds__(256) void k_gemm(const void* __restrict__ Aptr,
                                              const ushort* __restrict__ WT,
                                              const float* __restrict__ rowscale,
                                              ushort* __restrict__ H, int M, int K) {
    __shared__ ushort As[128][40];  // pad 40: <=2-way bank conflict (free)
    __shared__ ushort Bs[128][40];

    const int tid = threadIdx.x;
    const int wid = tid >> 6, lane = tid & 63;
    const int wr = wid >> 1, wc = wid & 1;
    const int lr = lane & 15, lk = (lane >> 4) * 8;
    const int rowbase = blockIdx.x * 128;

    f32x4 acc[4][4];
#pragma unroll
    for (int i = 0; i < 4; i++)
#pragma unroll
        for (int j = 0; j < 4; j++) acc[i][j] = (f32x4)0.f;

    const int sr = tid >> 1;
    const int sh = (tid & 1) * 16;

    for (int k0 = 0; k0 < K; k0 += 32) {
        {
            int gr = rowbase + sr;
            ushort tmp[16];
            if (A_F32) {
                const float* A = (const float*)Aptr;
                if (gr < M) {
                    const float* p = A + (size_t)gr * K + k0 + sh;
#pragma unroll
                    for (int q = 0; q < 4; q++) {
                        float4 v = *(const float4*)(p + q * 4);
                        tmp[q * 4 + 0] = f2b(v.x); tmp[q * 4 + 1] = f2b(v.y);
                        tmp[q * 4 + 2] = f2b(v.z); tmp[q * 4 + 3] = f2b(v.w);
                    }
                } else {
#pragma unroll
                    for (int q = 0; q < 16; q++) tmp[q] = 0;
                }
            } else {
                const ushort* A = (const ushort*)Aptr;
                if (gr < M) {
                    const ushort* p = A + (size_t)gr * K + k0 + sh;
                    *(short8*)&tmp[0] = *(const short8*)(p);
                    *(short8*)&tmp[8] = *(const short8*)(p + 8);
                } else {
#pragma unroll
                    for (int q = 0; q < 16; q++) tmp[q] = 0;
                }
            }
            *(short8*)&As[sr][sh]     = *(short8*)&tmp[0];
            *(short8*)&As[sr][sh + 8] = *(short8*)&tmp[8];
        }
        {
#pragma unroll
            for (int t = 0; t < 2; t++) {
                int c = tid + t * 256;
                int row = c >> 2, q = c & 3;
                short8 v = *(const short8*)(WT + (size_t)row * K + k0 + q * 8);
                *(short8*)&Bs[row][q * 8] = v;
            }
        }
        __syncthreads();

        short8 af[4], bfv[4];
#pragma unroll
        for (int i = 0; i < 4; i++) af[i] = *(const short8*)&As[wr * 64 + i * 16 + lr][lk];
#pragma unroll
        for (int j = 0; j < 4; j++) bfv[j] = *(const short8*)&Bs[wc * 64 + j * 16 + lr][lk];
#pragma unroll
        for (int i = 0; i < 4; i++)
#pragma unroll
            for (int j = 0; j < 4; j++)
                acc[i][j] = __builtin_amdgcn_mfma_f32_16x16x32_bf16(af[i], bfv[j], acc[i][j], 0, 0, 0);
        __syncthreads();
    }

#pragma unroll
    for (int i = 0; i < 4; i++) {
#pragma unroll
        for (int r = 0; r < 4; r++) {
            int row = rowbase + wr * 64 + i * 16 + (lane >> 4) * 4 + r;
            if (row < M) {
                float sc = rowscale[row];
#pragma unroll
                for (int j = 0; j < 4; j++) {
                    int colg = wc * 64 + j * 16 + lr;
                    H[(size_t)row * 128 + colg] = f2b(acc[i][j][r] * sc);
                }
            }
        }
    }
}

// ---------------- gather batch helper: B independent row-loads in flight ----------------

template<int B>
static __device__ __forceinline__ void gbatch(const ushort* __restrict__ h, int lx, int myc,
                                              int j, float& a0, float& a1) {
    uint pk[B];
#pragma unroll
    for (int q = 0; q < B; q++) {
        int s = __shfl(myc, j + q);
        pk[q] = *(const uint*)(h + (size_t)s * 128 + lx);
    }
#pragma unroll
    for (int q = 0; q < B; q++) {
        a0 += b2f(pk[q] & 0xffffu);
        a1 += b2f(pk[q] >> 16);
    }
}

static __device__ __forceinline__ void gather_node(const ushort* __restrict__ h, int lx,
                                                   const int* __restrict__ col, int lane,
                                                   int e0, int e1, float& a0, float& a1) {
    for (int base = e0; base < e1; base += 64) {
        int cnt = e1 - base; if (cnt > 64) cnt = 64;
        int myc = (base + lane < e1) ? col[base + lane] : 0;
        int j = 0;
        while (j + 32 <= cnt) { gbatch<32>(h, lx, myc, j, a0, a1); j += 32; }
        if (j + 16 <= cnt) { gbatch<16>(h, lx, myc, j, a0, a1); j += 16; }
        if (j + 8 <= cnt)  { gbatch<8>(h, lx, myc, j, a0, a1);  j += 8; }
        if (j + 4 <= cnt)  { gbatch<4>(h, lx, myc, j, a0, a1);  j += 4; }
        if (j + 2 <= cnt)  { gbatch<2>(h, lx, myc, j, a0, a1);  j += 2; }
        if (j < cnt)       { gbatch<1>(h, lx, myc, j, a0, a1); }
    }
}

// ---------------- layer-1 aggregation: wave per node, bf16 out ----------------
// h rows pre-scaled by dinv[src]; out[v] = relu( dinv[v]*sum h'[s] + b )

__global__ __launch_bounds__(256) void k_agg(const ushort* __restrict__ h,
                                             const int* __restrict__ offs,
                                             const int* __restrict__ col,
                                             const float* __restrict__ dinv,
                                             const float* __restrict__ bias,
                                             ushort* __restrict__ outp, int n) {
    int wid = threadIdx.x >> 6, lane = threadIdx.x & 63;
    int v = blockIdx.x * 4 + wid;
    if (v >= n) return;
    int e0 = offs[v], e1 = offs[v + 1];
    int lx = lane * 2;
    float a0 = 0.f, a1 = 0.f;
    gather_node(h, lx, col, lane, e0, e1, a0, a1);
    float dvv = dinv[v];
    float r0 = fmaxf(fmaf(a0, dvv, bias[lx + 0]), 0.f);
    float r1 = fmaxf(fmaf(a1, dvv, bias[lx + 1]), 0.f);
    uint pk = (uint)f2b(r0) | ((uint)f2b(r1) << 16);
    *(uint*)(outp + (size_t)v * 128 + lx) = pk;
}

// ---------------- layer-2 aggregation fused with classifier + log_softmax ----------------

__global__ __launch_bounds__(256) void k_agg_cls(const ushort* __restrict__ h,
                                                 const int* __restrict__ offs,
                                                 const int* __restrict__ col,
                                                 const float* __restrict__ dinv,
                                                 const float* __restrict__ bias,
                                                 const float* __restrict__ Wc,
                                                 const float* __restrict__ bc,
                                                 float* __restrict__ out, int n) {
    __shared__ float Ws[128 * 16];
    __shared__ float shh[4][128];
    int tid = threadIdx.x;
#pragma unroll
    for (int t = 0; t < 8; t++) Ws[tid + 256 * t] = Wc[tid + 256 * t];
    __syncthreads();

    int wid = tid >> 6, lane = tid & 63;
    int v = blockIdx.x * 4 + wid;
    bool valid = v < n;
    int e0 = 0, e1 = 0;
    if (valid) { e0 = offs[v]; e1 = offs[v + 1]; }
    int lx = lane * 2;
    float a0 = 0.f, a1 = 0.f;
    gather_node(h, lx, col, lane, e0, e1, a0, a1);
    float dvv = valid ? dinv[v] : 0.f;
    float r0 = fmaxf(fmaf(a0, dvv, bias[lx + 0]), 0.f);
    float r1 = fmaxf(fmaf(a1, dvv, bias[lx + 1]), 0.f);
    shh[wid][lx] = r0;
    shh[wid][lx + 1] = r1;
    __syncthreads();

    // classifier: j = class, c = feature chunk (32 feats each)
    int j = lane & 15, c = lane >> 4;
    float acc = 0.f;
#pragma unroll
    for (int f0 = 0; f0 < 32; f0++) {
        int f = c * 32 + f0;
        acc = fmaf(shh[wid][f], Ws[f * 16 + j], acc);
    }
    acc += __shfl_xor(acc, 16);
    acc += __shfl_xor(acc, 32);
    acc += bc[j];

    float m = acc;
#pragma unroll
    for (int o = 8; o >= 1; o >>= 1) m = fmaxf(m, __shfl_xor(m, o));
    float s = expf(acc - m);
#pragma unroll
    for (int o = 8; o >= 1; o >>= 1) s += __shfl_xor(s, o);
    if (valid && lane < 16) out[(size_t)v * 16 + j] = acc - m - logf(s);
}

// ---------------- launch ----------------

extern "C" void kernel_launch(void* const* d_in, const int* in_sizes, int n_in,
                              void* d_out, int out_size, void* d_ws, size_t ws_size,
                              hipStream_t stream) {
    const float* x  = (const float*)d_in[0];
    const int* eidx = (const int*)d_in[1];
    const float* W1 = (const float*)d_in[2];
    const float* b1 = (const float*)d_in[3];
    const float* W2 = (const float*)d_in[4];
    const float* b2 = (const float*)d_in[5];
    const float* Wc = (const float*)d_in[6];
    const float* bc = (const float*)d_in[7];
    float* out = (float*)d_out;

    const int N = in_sizes[0] / NFEAT;   // 50000
    const int E = in_sizes[1] / 2;       // 800000
    const int* src = eidx;
    const int* dst = eidx + E;

    char* p = (char*)d_ws;
    auto alloc = [&](size_t bytes) { char* r = p; p += (bytes + 255) & ~(size_t)255; return r; };
    int*    deg    = (int*)   alloc((size_t)N * 4);
    float*  dinv   = (float*) alloc((size_t)N * 4);
    int*    offs   = (int*)   alloc((size_t)(N + 1) * 4);
    int*    cursor = (int*)   alloc((size_t)N * 4);
    int*    col    = (int*)   alloc((size_t)(E + N) * 4);
    int*    bsum   = (int*)   alloc((size_t)256 * 4);
    ushort* W1T    = (ushort*)alloc((size_t)128 * NFEAT * 2);
    ushort* W2T    = (ushort*)alloc((size_t)128 * NHID * 2);
    ushort* bufA   = (ushort*)alloc((size_t)N * NHID * 2);   // h1' then h2'
    ushort* g1b    = (ushort*)alloc((size_t)N * NHID * 2);   // agg1 output (bf16)

    const int nb = (N + SCAN_BS - 1) / SCAN_BS;

    k_init_deg<<<(N + 255) / 256, 256, 0, stream>>>(deg, N);
    k_count<<<(E + 255) / 256, 256, 0, stream>>>(dst, E, deg);
    k_dinv<<<(N + 255) / 256, 256, 0, stream>>>(deg, dinv, cursor, N);
    k_scan1<<<nb, SCAN_BS, 0, stream>>>(deg, offs, bsum, N);
    k_scan2<<<1, 64, 0, stream>>>(bsum, offs, nb, N);
    k_scan3<<<nb, SCAN_BS, 0, stream>>>(offs, bsum, N);
    k_fill_edges<<<(E + 255) / 256, 256, 0, stream>>>(src, dst, E, offs, cursor, col);
    k_fill_self<<<(N + 255) / 256, 256, 0, stream>>>(offs, cursor, col, N);

    k_tcast<<<(NFEAT * 128 + 255) / 256, 256, 0, stream>>>(W1, W1T, NFEAT);
    k_tcast<<<(NHID * 128 + 255) / 256, 256, 0, stream>>>(W2, W2T, NHID);

    const int gblocks = (N + 127) / 128;
    // layer 1
    k_gemm<1><<<gblocks, 256, 0, stream>>>(x, W1T, dinv, bufA, N, NFEAT);
    k_agg<<<(N + 3) / 4, 256, 0, stream>>>(bufA, offs, col, dinv, b1, g1b, N);
    // layer 2
    k_gemm<0><<<gblocks, 256, 0, stream>>>(g1b, W2T, dinv, bufA, N, NHID);
    // layer-2 aggregation + classifier + log_softmax fused
    k_agg_cls<<<(N + 3) / 4, 256, 0, stream>>>(bufA, offs, col, dinv, b2, Wc, bc, out, N);
}